// Round 1
// baseline (454.066 us; speedup 1.0000x reference)
//
#include <hip/hip_runtime.h>
#include <hip/hip_bf16.h>

// Problem constants
constexpr int BB = 32;     // batch
constexpr int NN = 4096;   // tokens
constexpr int CC = 128;    // feat channels
constexpr int DD = 64;     // slot dim
constexpr int KK = 8;      // slots (slot 0 = bg, 1..7 = fg)
constexpr int HH = 128;    // mlp hidden
constexpr float SCALE = 0.125f;   // D^-0.5
constexpr float EPS_A = 1e-8f;
constexpr float LN_EPS = 1e-5f;

constexpr int K1_ROWS = 64;       // rows per K1 block
constexpr int NT = 16;            // n-tiles per batch in K2
constexpr int TILE_N = 256;       // n per K2 block

__device__ inline float wave_sum(float x) {
#pragma unroll
    for (int off = 32; off > 0; off >>= 1) x += __shfl_xor(x, off, 64);
    return x;
}

__device__ inline float sigmoidf_(float x) { return 1.f / (1.f + __expf(-x)); }

// ---------------------------------------------------------------------------
// K1: x = LN(feat); kT[b][d][n] = (x@Wk)^T ; v[b][n][d] = x@Wv
// Block: 512 thr (8 waves), 64 rows. Wk/Wv staged in LDS; xhat broadcast from
// LDS; each lane owns output d. kT stores staged through padded LDS so the
// global writes are 256B-contiguous per d-row.
// ---------------------------------------------------------------------------
__global__ __launch_bounds__(512) void k1_lnkv(
    const float* __restrict__ feat, const float* __restrict__ nf_g,
    const float* __restrict__ nf_b, const float* __restrict__ Wk,
    const float* __restrict__ Wv, float* __restrict__ kT,
    float* __restrict__ vout)
{
    __shared__ float wk_s[CC * DD];          // 32 KB
    __shared__ float wv_s[CC * DD];          // 32 KB
    __shared__ float xh[K1_ROWS][CC];        // 32 KB
    __shared__ float ks[DD][K1_ROWS + 1];    // 16.25 KB (padded: conflict-free transpose)

    const int tid = threadIdx.x, wave = tid >> 6, lane = tid & 63;

    for (int t = tid; t < CC * DD / 4; t += 512) {
        ((float4*)wk_s)[t] = ((const float4*)Wk)[t];
        ((float4*)wv_s)[t] = ((const float4*)Wv)[t];
    }

    const size_t row0 = (size_t)blockIdx.x * K1_ROWS;
    const float g0 = nf_g[lane], g1 = nf_g[lane + 64];
    const float b0 = nf_b[lane], b1 = nf_b[lane + 64];

    // LN: each wave handles 8 rows; row = 128 elems = 2 per lane
#pragma unroll
    for (int r = 0; r < 8; r++) {
        const int row = wave * 8 + r;
        const float* fp = feat + (row0 + row) * CC;
        const float x0 = fp[lane], x1 = fp[lane + 64];
        const float m = wave_sum(x0 + x1) * (1.f / 128.f);
        const float d0 = x0 - m, d1 = x1 - m;
        const float var = wave_sum(d0 * d0 + d1 * d1) * (1.f / 128.f);
        const float rstd = rsqrtf(var + LN_EPS);
        xh[row][lane] = d0 * rstd * g0 + b0;
        xh[row][lane + 64] = d1 * rstd * g1 + b1;
    }
    __syncthreads();

    // Matvec: lane owns d; 8 rows per wave; c unrolled x4 with float4 broadcasts
    float ak[8], av[8];
#pragma unroll
    for (int r = 0; r < 8; r++) { ak[r] = 0.f; av[r] = 0.f; }
    const int rb = wave * 8;
    for (int c = 0; c < CC; c += 4) {
        float wkc[4], wvc[4];
#pragma unroll
        for (int cc = 0; cc < 4; cc++) {
            wkc[cc] = wk_s[(c + cc) * DD + lane];
            wvc[cc] = wv_s[(c + cc) * DD + lane];
        }
#pragma unroll
        for (int r = 0; r < 8; r++) {
            const float4 x4 = *(const float4*)&xh[rb + r][c];
            ak[r] += x4.x * wkc[0]; ak[r] += x4.y * wkc[1];
            ak[r] += x4.z * wkc[2]; ak[r] += x4.w * wkc[3];
            av[r] += x4.x * wvc[0]; av[r] += x4.y * wvc[1];
            av[r] += x4.z * wvc[2]; av[r] += x4.w * wvc[3];
        }
    }

#pragma unroll
    for (int r = 0; r < 8; r++) {
        const size_t row = row0 + rb + r;
        vout[row * DD + lane] = av[r];     // coalesced
        ks[lane][rb + r] = ak[r];          // padded stride 65 -> conflict-free
    }
    __syncthreads();

    const int b = (int)(row0 / NN);
    const int n0 = (int)(row0 % NN);
    for (int t = tid; t < DD * K1_ROWS; t += 512) {
        const int d = t / K1_ROWS, nn = t % K1_ROWS;
        kT[((size_t)b * DD + d) * NN + n0 + nn] = ks[d][nn];
    }
}

// ---------------------------------------------------------------------------
// K2: dots = q@kT * SCALE; softmax over slots (lane-local, 8 vals); attn+=EPS;
// partial S[i] = sum_n attn, partial U[i][d] = sum_n attn*v. One block per
// (b, 256-n tile); deterministic per-block partials (no atomics).
// ---------------------------------------------------------------------------
__global__ __launch_bounds__(256) void k2_attn(
    const float* __restrict__ kT, const float* __restrict__ v,
    const float* __restrict__ q, float* __restrict__ Upart,
    float* __restrict__ Spart, float* __restrict__ attn_out)
{
    __shared__ float qT[DD][KK];             // 2 KB  (qT[d][i])
    __shared__ float al[TILE_N][KK];         // 8 KB  attn tile
    __shared__ float Ur[4][KK * DD];         // 8 KB  per-wave U partials
    __shared__ float Sr[4][KK];

    const int tid = threadIdx.x, wave = tid >> 6, lane = tid & 63;
    const int b = blockIdx.x / NT, tile = blockIdx.x % NT;
    const int n0 = tile * TILE_N;

    for (int t = tid; t < KK * DD; t += 256) qT[t % DD][t / DD] = q[b * KK * DD + t];
    __syncthreads();

    // phase 1: lane owns n
    const int n = n0 + wave * 64 + lane;
    float dots[KK];
#pragma unroll
    for (int i = 0; i < KK; i++) dots[i] = 0.f;
    const float* kp = kT + (size_t)b * DD * NN + n;
#pragma unroll 8
    for (int d = 0; d < DD; d++) {
        const float kv = kp[(size_t)d * NN];
        const float4 q0 = *(const float4*)&qT[d][0];
        const float4 q1 = *(const float4*)&qT[d][4];
        dots[0] += kv * q0.x; dots[1] += kv * q0.y;
        dots[2] += kv * q0.z; dots[3] += kv * q0.w;
        dots[4] += kv * q1.x; dots[5] += kv * q1.y;
        dots[6] += kv * q1.z; dots[7] += kv * q1.w;
    }
    float m = -1e30f;
#pragma unroll
    for (int i = 0; i < KK; i++) { dots[i] *= SCALE; m = fmaxf(m, dots[i]); }
    float s = 0.f, e[KK];
#pragma unroll
    for (int i = 0; i < KK; i++) { e[i] = __expf(dots[i] - m); s += e[i]; }
    const float inv = 1.f / s;
    float a[KK], sv[KK];
#pragma unroll
    for (int i = 0; i < KK; i++) { a[i] = e[i] * inv + EPS_A; sv[i] = a[i]; }

    const int nl = wave * 64 + lane;
    *(float4*)&al[nl][0] = make_float4(a[0], a[1], a[2], a[3]);
    *(float4*)&al[nl][4] = make_float4(a[4], a[5], a[6], a[7]);
    if (attn_out) {
#pragma unroll
        for (int i = 0; i < KK; i++)
            attn_out[((size_t)b * KK + i) * NN + n] = a[i];
    }
#pragma unroll
    for (int off = 32; off > 0; off >>= 1) {
#pragma unroll
        for (int i = 0; i < KK; i++) sv[i] += __shfl_xor(sv[i], off, 64);
    }
    if (lane == 0) {
#pragma unroll
        for (int i = 0; i < KK; i++) Sr[wave][i] = sv[i];
    }
    __syncthreads();

    // phase 2: lane owns d; wave iterates its 64 n
    float U[KK];
#pragma unroll
    for (int i = 0; i < KK; i++) U[i] = 0.f;
    const float* vp = v + ((size_t)b * NN + n0 + wave * 64) * DD + lane;
#pragma unroll 4
    for (int t = 0; t < 64; t++) {
        const float vv = vp[t * DD];
        const float4 a0 = *(const float4*)&al[wave * 64 + t][0];
        const float4 a1 = *(const float4*)&al[wave * 64 + t][4];
        U[0] += a0.x * vv; U[1] += a0.y * vv; U[2] += a0.z * vv; U[3] += a0.w * vv;
        U[4] += a1.x * vv; U[5] += a1.y * vv; U[6] += a1.z * vv; U[7] += a1.w * vv;
    }
#pragma unroll
    for (int i = 0; i < KK; i++) Ur[wave][i * DD + lane] = U[i];
    __syncthreads();

    for (int t = tid; t < KK * DD; t += 256) {
        Upart[(size_t)blockIdx.x * KK * DD + t] =
            Ur[0][t] + Ur[1][t] + Ur[2][t] + Ur[3][t];
    }
    if (tid < KK)
        Spart[blockIdx.x * KK + tid] =
            Sr[0][tid] + Sr[1][tid] + Sr[2][tid] + Sr[3][tid];
}

// ---------------------------------------------------------------------------
// K3: reduce partials -> upd = U/S; GRU + residual MLP slot update; compute
// next q = LN(slots) @ Wq (per-slot bg/fg weight selection). One block per b.
// do_update==0: just slots_cur = h_in and q-gen (initial iteration).
// ---------------------------------------------------------------------------
__global__ __launch_bounds__(256) void k3_update(
    const float* __restrict__ Upart, const float* __restrict__ Spart,
    const float* __restrict__ h_in, float* __restrict__ slots_cur,
    float* __restrict__ qout,
    const float* __restrict__ gru_wih, const float* __restrict__ gru_whh,
    const float* __restrict__ gru_bih, const float* __restrict__ gru_bhh,
    const float* __restrict__ gbg_wih, const float* __restrict__ gbg_whh,
    const float* __restrict__ gbg_bih, const float* __restrict__ gbg_bhh,
    const float* __restrict__ res_g, const float* __restrict__ res_b,
    const float* __restrict__ res_w1, const float* __restrict__ res_b1,
    const float* __restrict__ res_w2, const float* __restrict__ res_b2,
    const float* __restrict__ rbg_g, const float* __restrict__ rbg_b,
    const float* __restrict__ rbg_w1, const float* __restrict__ rbg_b1,
    const float* __restrict__ rbg_w2, const float* __restrict__ rbg_b2,
    const float* __restrict__ qln_g, const float* __restrict__ qln_b,
    const float* __restrict__ Wq, const float* __restrict__ qbg_g,
    const float* __restrict__ qbg_b, const float* __restrict__ Wqbg,
    float* __restrict__ out_slots, int do_update)
{
    const int b = blockIdx.x, tid = threadIdx.x;
    __shared__ float h[KK][DD], upd[KK][DD], gi[KK][3 * DD], gh[KK][3 * DD],
        tmp[KK][DD], lnx[KK][DD], h1[KK][HH], Sls[KK], mn[KK], rstd[KK];

    for (int t = tid; t < KK * DD; t += 256)
        ((float*)h)[t] = h_in[(size_t)b * KK * DD + t];
    __syncthreads();

    if (do_update) {
        if (tid < KK) {
            float sacc = 0.f;
            for (int p = 0; p < NT; p++) sacc += Spart[(b * NT + p) * KK + tid];
            Sls[tid] = sacc;
        }
        __syncthreads();
        for (int t = tid; t < KK * DD; t += 256) {
            float sacc = 0.f;
            for (int p = 0; p < NT; p++)
                sacc += Upart[(size_t)(b * NT + p) * KK * DD + t];
            ((float*)upd)[t] = sacc / Sls[t / DD];
        }
        __syncthreads();

        // GRU gates: gi = upd@wih^T + bih ; gh = h@whh^T + bhh
        for (int idx = tid; idx < KK * 3 * DD; idx += 256) {
            const int i = idx / (3 * DD), j = idx % (3 * DD);
            const float* wih = i ? gru_wih : gbg_wih;
            const float* whh = i ? gru_whh : gbg_whh;
            float si = 0.f, sh = 0.f;
#pragma unroll 8
            for (int d = 0; d < DD; d++) {
                si += upd[i][d] * wih[j * DD + d];
                sh += h[i][d] * whh[j * DD + d];
            }
            gi[i][j] = si + (i ? gru_bih : gbg_bih)[j];
            gh[i][j] = sh + (i ? gru_bhh : gbg_bhh)[j];
        }
        __syncthreads();
        for (int t = tid; t < KK * DD; t += 256) {
            const int i = t / DD, d = t % DD;
            const float r = sigmoidf_(gi[i][d] + gh[i][d]);
            const float z = sigmoidf_(gi[i][DD + d] + gh[i][DD + d]);
            const float ng = tanhf(gi[i][2 * DD + d] + r * gh[i][2 * DD + d]);
            tmp[i][d] = (1.f - z) * ng + z * h[i][d];
        }
        __syncthreads();

        // residual MLP: s + relu(LN(s)@w1 + b1)@w2 + b2
        if (tid < KK) {
            float m = 0.f;
            for (int d = 0; d < DD; d++) m += tmp[tid][d];
            m *= (1.f / DD);
            float vv = 0.f;
            for (int d = 0; d < DD; d++) { const float dd = tmp[tid][d] - m; vv += dd * dd; }
            vv *= (1.f / DD);
            mn[tid] = m; rstd[tid] = rsqrtf(vv + LN_EPS);
        }
        __syncthreads();
        for (int t = tid; t < KK * DD; t += 256) {
            const int i = t / DD, d = t % DD;
            lnx[i][d] = (tmp[i][d] - mn[i]) * rstd[i] * (i ? res_g : rbg_g)[d] +
                        (i ? res_b : rbg_b)[d];
        }
        __syncthreads();
        for (int t = tid; t < KK * HH; t += 256) {
            const int i = t / HH, j = t % HH;
            const float* w1 = i ? res_w1 : rbg_w1;
            float sacc = (i ? res_b1 : rbg_b1)[j];
#pragma unroll 8
            for (int d = 0; d < DD; d++) sacc += lnx[i][d] * w1[d * HH + j];
            h1[i][j] = fmaxf(sacc, 0.f);
        }
        __syncthreads();
        for (int t = tid; t < KK * DD; t += 256) {
            const int i = t / DD, d = t % DD;
            const float* w2 = i ? res_w2 : rbg_w2;
            float sacc = (i ? res_b2 : rbg_b2)[d];
#pragma unroll 8
            for (int j = 0; j < HH; j++) sacc += h1[i][j] * w2[j * DD + d];
            h[i][d] = tmp[i][d] + sacc;   // h now holds the new slots
        }
        __syncthreads();
    }

    for (int t = tid; t < KK * DD; t += 256) {
        const float vvv = ((float*)h)[t];
        slots_cur[(size_t)b * KK * DD + t] = vvv;
        if (out_slots) out_slots[(size_t)b * KK * DD + t] = vvv;
    }

    // next q: LN(slots) with q/qbg LN params, then @ Wq / Wq_bg
    if (tid < KK) {
        float m = 0.f;
        for (int d = 0; d < DD; d++) m += h[tid][d];
        m *= (1.f / DD);
        float vv = 0.f;
        for (int d = 0; d < DD; d++) { const float dd = h[tid][d] - m; vv += dd * dd; }
        vv *= (1.f / DD);
        mn[tid] = m; rstd[tid] = rsqrtf(vv + LN_EPS);
    }
    __syncthreads();
    for (int t = tid; t < KK * DD; t += 256) {
        const int i = t / DD, d = t % DD;
        lnx[i][d] = (h[i][d] - mn[i]) * rstd[i] * (i ? qln_g : qbg_g)[d] +
                    (i ? qln_b : qbg_b)[d];
    }
    __syncthreads();
    for (int t = tid; t < KK * DD; t += 256) {
        const int i = t / DD, d = t % DD;
        const float* W = i ? Wq : Wqbg;
        float sacc = 0.f;
#pragma unroll 8
        for (int e2 = 0; e2 < DD; e2++) sacc += lnx[i][e2] * W[e2 * DD + d];
        qout[(size_t)b * KK * DD + t] = sacc;
    }
}

// ---------------------------------------------------------------------------
extern "C" void kernel_launch(void* const* d_in, const int* in_sizes, int n_in,
                              void* d_out, int out_size, void* d_ws, size_t ws_size,
                              hipStream_t stream)
{
    const float* feat    = (const float*)d_in[0];
    const float* slot_in = (const float*)d_in[1];
    const float* nf_g    = (const float*)d_in[2];
    const float* nf_b    = (const float*)d_in[3];
    const float* Wk      = (const float*)d_in[4];
    const float* Wv      = (const float*)d_in[5];
    const float* qln_g   = (const float*)d_in[6];
    const float* qln_b   = (const float*)d_in[7];
    const float* Wq      = (const float*)d_in[8];
    const float* qbg_g   = (const float*)d_in[9];
    const float* qbg_b   = (const float*)d_in[10];
    const float* Wqbg    = (const float*)d_in[11];
    const float* gru_wih = (const float*)d_in[12];
    const float* gru_whh = (const float*)d_in[13];
    const float* gru_bih = (const float*)d_in[14];
    const float* gru_bhh = (const float*)d_in[15];
    const float* gbg_wih = (const float*)d_in[16];
    const float* gbg_whh = (const float*)d_in[17];
    const float* gbg_bih = (const float*)d_in[18];
    const float* gbg_bhh = (const float*)d_in[19];
    const float* res_g   = (const float*)d_in[20];
    const float* res_b   = (const float*)d_in[21];
    const float* res_w1  = (const float*)d_in[22];
    const float* res_b1  = (const float*)d_in[23];
    const float* res_w2  = (const float*)d_in[24];
    const float* res_b2  = (const float*)d_in[25];
    const float* rbg_g   = (const float*)d_in[26];
    const float* rbg_b   = (const float*)d_in[27];
    const float* rbg_w1  = (const float*)d_in[28];
    const float* rbg_b1  = (const float*)d_in[29];
    const float* rbg_w2  = (const float*)d_in[30];
    const float* rbg_b2  = (const float*)d_in[31];

    float* out = (float*)d_out;
    char* ws = (char*)d_ws;
    size_t off = 0;
    float* kT    = (float*)(ws + off); off += (size_t)BB * DD * NN * 4;
    float* v     = (float*)(ws + off); off += (size_t)BB * NN * DD * 4;
    float* q     = (float*)(ws + off); off += (size_t)BB * KK * DD * 4;
    float* slots = (float*)(ws + off); off += (size_t)BB * KK * DD * 4;
    float* Upart = (float*)(ws + off); off += (size_t)BB * NT * KK * DD * 4;
    float* Spart = (float*)(ws + off); off += (size_t)BB * NT * KK * 4;
    if (off > ws_size) return;  // loud failure rather than corruption

    float* out_slots = out;                 // [B][K][D]
    float* out_attn  = out + BB * KK * DD;  // [B][K][N]

    k1_lnkv<<<BB * NN / K1_ROWS, 512, 0, stream>>>(feat, nf_g, nf_b, Wk, Wv, kT, v);

    // init: slots = slot_in, q from initial slots
    k3_update<<<BB, 256, 0, stream>>>(
        Upart, Spart, slot_in, slots, q,
        gru_wih, gru_whh, gru_bih, gru_bhh, gbg_wih, gbg_whh, gbg_bih, gbg_bhh,
        res_g, res_b, res_w1, res_b1, res_w2, res_b2,
        rbg_g, rbg_b, rbg_w1, rbg_b1, rbg_w2, rbg_b2,
        qln_g, qln_b, Wq, qbg_g, qbg_b, Wqbg, nullptr, 0);

    for (int it = 0; it < 3; it++) {
        k2_attn<<<BB * NT, 256, 0, stream>>>(
            kT, v, q, Upart, Spart, it == 2 ? out_attn : nullptr);
        k3_update<<<BB, 256, 0, stream>>>(
            Upart, Spart, slots, slots, q,
            gru_wih, gru_whh, gru_bih, gru_bhh, gbg_wih, gbg_whh, gbg_bih, gbg_bhh,
            res_g, res_b, res_w1, res_b1, res_w2, res_b2,
            rbg_g, rbg_b, rbg_w1, rbg_b1, rbg_w2, rbg_b2,
            qln_g, qln_b, Wq, qbg_g, qbg_b, Wqbg,
            it == 2 ? out_slots : nullptr, 1);
    }
}

// Round 2
// 273.155 us; speedup vs baseline: 1.6623x; 1.6623x over previous
//
#include <hip/hip_runtime.h>
#include <hip/hip_bf16.h>

// Problem constants
constexpr int BB = 32;     // batch
constexpr int NN = 4096;   // tokens
constexpr int CC = 128;    // feat channels
constexpr int DD = 64;     // slot dim
constexpr int KK = 8;      // slots (slot 0 = bg, 1..7 = fg)
constexpr int HH = 128;    // mlp hidden
constexpr float SCALE = 0.125f;   // D^-0.5
constexpr float EPS_A = 1e-8f;
constexpr float LN_EPS = 1e-5f;

constexpr int NT = 16;            // n-tiles per batch in K2
constexpr int TILE_N = 256;       // n per K2 block

typedef __bf16 bfx8 __attribute__((ext_vector_type(8)));
typedef float f32x4 __attribute__((ext_vector_type(4)));

__device__ inline float wave_sum(float x) {
#pragma unroll
    for (int off = 32; off > 0; off >>= 1) x += __shfl_xor(x, off, 64);
    return x;
}

__device__ inline float sigmoidf_(float x) { return 1.f / (1.f + __expf(-x)); }

// round-to-nearest-even bf16 (bit trick; inputs finite & moderate)
__device__ inline unsigned short bf16rne(float x) {
    unsigned u = __float_as_uint(x);
    unsigned r = u + 0x7fffu + ((u >> 16) & 1u);
    return (unsigned short)(r >> 16);
}
__device__ inline float bf16tof(unsigned short h) {
    return __uint_as_float(((unsigned)h) << 16);
}

// ---------------------------------------------------------------------------
// K0: build fragment-linear bf16 W = [Wk | Wv]  (shape [C=128][N=128]).
// fragW layout: [ks(4)][nf(8)][lane(64)][j(8)] bf16, where the element is
// W[ks*32 + (lane>>4)*8 + j][nf*16 + (lane&15)].  16384 elems = 32 KB.
// ---------------------------------------------------------------------------
__global__ __launch_bounds__(256) void k0_prepw(
    const float* __restrict__ Wk, const float* __restrict__ Wv,
    unsigned short* __restrict__ fragW)
{
    const int o = blockIdx.x * 256 + threadIdx.x;   // < 16384
    const int j = o & 7, l = (o >> 3) & 63, nf = (o >> 9) & 7, ks = o >> 12;
    const int c = ks * 32 + ((l >> 4) << 3) + j;
    const int n = nf * 16 + (l & 15);
    const float w = (n < DD) ? Wk[c * DD + n] : Wv[c * DD + (n - DD)];
    fragW[o] = bf16rne(w);
}

// ---------------------------------------------------------------------------
// K1: x = LN(feat); [k|v] = x @ W via bf16 MFMA with 2-term split (x_hi+x_lo).
// Block 256 thr (4 waves), tile M=64 rows, N=128 (k cols 0-63, v cols 64-127).
// LDS: fragW 32KB + union{xh_hi/lo bf16 (32KB) ; ks transpose fp32 (16.6KB)}.
// xh uses XOR-16B swizzle (T2) so A-frag ds_read_b128 is conflict-free.
// ---------------------------------------------------------------------------
__global__ __launch_bounds__(256, 2) void k1_mfma(
    const float* __restrict__ feat, const float* __restrict__ nf_g,
    const float* __restrict__ nf_b, const unsigned short* __restrict__ fragW,
    float* __restrict__ kT, float* __restrict__ vout)
{
    __shared__ unsigned short wlds[16384];   // 32 KB frag-linear W
    __shared__ char ubuf[32768];             // union: xh_hi|xh_lo  /  ks[64][65]

    const int tid = threadIdx.x, w = tid >> 6, lane = tid & 63;

    // stage fragW (L2-resident after first blocks)
#pragma unroll
    for (int t = 0; t < 8; t++)
        ((uint4*)wlds)[t * 256 + tid] = ((const uint4*)fragW)[t * 256 + tid];

    const size_t row0 = (size_t)blockIdx.x * 64;
    const float g0 = nf_g[lane], g1 = nf_g[lane + 64];
    const float b0 = nf_b[lane], b1 = nf_b[lane + 64];

    unsigned short* xh_hi = (unsigned short*)ubuf;            // [64][128] bf16 swz
    unsigned short* xh_lo = (unsigned short*)(ubuf + 16384);

    // LN: wave w handles rows w*16 .. w*16+15; row = 128 elems = 2/lane
#pragma unroll 4
    for (int r0 = 0; r0 < 16; r0++) {
        const int r = w * 16 + r0;
        const float* fp = feat + (row0 + r) * CC;
        const float x0 = fp[lane], x1 = fp[lane + 64];
        const float m = wave_sum(x0 + x1) * (1.f / 128.f);
        const float d0 = x0 - m, d1 = x1 - m;
        const float var = wave_sum(d0 * d0 + d1 * d1) * (1.f / 128.f);
        const float rs = rsqrtf(var + LN_EPS);
        const float y0 = d0 * rs * g0 + b0;
        const float y1 = d1 * rs * g1 + b1;
        const int sw = (r & 7) << 4;
        const unsigned short h0 = bf16rne(y0), h1 = bf16rne(y1);
        const unsigned short l0 = bf16rne(y0 - bf16tof(h0));
        const unsigned short l1 = bf16rne(y1 - bf16tof(h1));
        const int o0 = (r * 256 + (((2 * lane)) ^ sw)) >> 1;
        const int o1 = (r * 256 + (((2 * lane + 128)) ^ sw)) >> 1;
        xh_hi[o0] = h0; xh_hi[o1] = h1;
        xh_lo[o0] = l0; xh_lo[o1] = l1;
    }
    __syncthreads();

    // MFMA: wave w owns rows w*16..+15; 8 N-frags; 4 K-steps; 2 terms
    f32x4 acc[8];
#pragma unroll
    for (int nf = 0; nf < 8; nf++) acc[nf] = (f32x4){0.f, 0.f, 0.f, 0.f};

    const int arow = w * 16 + (lane & 15);
    const int hi16 = lane >> 4;
    const int asw = (arow & 7) << 4;
#pragma unroll
    for (int ks = 0; ks < 4; ks++) {
        const int abyte = arow * 256 + ((ks * 64 + hi16 * 16) ^ asw);
        const bfx8 ah = __builtin_bit_cast(bfx8, *(const uint4*)(ubuf + abyte));
        const bfx8 al = __builtin_bit_cast(bfx8, *(const uint4*)(ubuf + 16384 + abyte));
#pragma unroll
        for (int nf = 0; nf < 8; nf++) {
            const bfx8 bw = __builtin_bit_cast(
                bfx8, *(const uint4*)(wlds + ((ks * 8 + nf) * 64 + lane) * 8));
            acc[nf] = __builtin_amdgcn_mfma_f32_16x16x32_bf16(ah, bw, acc[nf], 0, 0, 0);
            acc[nf] = __builtin_amdgcn_mfma_f32_16x16x32_bf16(al, bw, acc[nf], 0, 0, 0);
        }
    }
    __syncthreads();   // xh dead; reuse ubuf as ks[64][65]

    float* kslds = (float*)ubuf;
    const int trow = w * 16 + (lane >> 4) * 4;   // C-frag: row=(lane>>4)*4+reg
    // k-part (nf 0..3) -> LDS transpose; v-part (nf 4..7) -> direct store
#pragma unroll
    for (int nf = 0; nf < 4; nf++) {
        const int d = nf * 16 + (lane & 15);
#pragma unroll
        for (int reg = 0; reg < 4; reg++)
            kslds[d * 65 + trow + reg] = acc[nf][reg];
    }
    {
        const size_t vbase = (row0 + trow) * DD + (lane & 15);
#pragma unroll
        for (int nf = 4; nf < 8; nf++) {
#pragma unroll
            for (int reg = 0; reg < 4; reg++)
                vout[vbase + (size_t)reg * DD + (nf - 4) * 16] = acc[nf][reg];
        }
    }
    __syncthreads();

    const int b = (int)(row0 >> 12);          // NN = 4096
    const int n0 = (int)(row0 & 4095);
#pragma unroll
    for (int t = 0; t < 16; t++) {
        const int idx = t * 256 + tid;
        const int d = idx >> 6, nn = idx & 63;
        kT[((size_t)b * DD + d) * NN + n0 + nn] = kslds[d * 65 + nn];
    }
}

// ---------------------------------------------------------------------------
// K2: dots = q@kT * SCALE; softmax over slots (lane-local, 8 vals); attn+=EPS;
// partial S[i] = sum_n attn, partial U[i][d] = sum_n attn*v. One block per
// (b, 256-n tile). Full 64-deep register preload of k and v (latency).
// ---------------------------------------------------------------------------
__global__ __launch_bounds__(256) void k2_attn(
    const float* __restrict__ kT, const float* __restrict__ v,
    const float* __restrict__ q, float* __restrict__ Upart,
    float* __restrict__ Spart, float* __restrict__ attn_out)
{
    __shared__ float qT[DD][KK];             // 2 KB  (qT[d][i])
    __shared__ float al[TILE_N][KK];         // 8 KB  attn tile
    __shared__ float Ur[4][KK * DD];         // 8 KB  per-wave U partials
    __shared__ float Sr[4][KK];

    const int tid = threadIdx.x, wave = tid >> 6, lane = tid & 63;
    const int b = blockIdx.x / NT, tile = blockIdx.x % NT;
    const int n0 = tile * TILE_N;

    for (int t = tid; t < KK * DD; t += 256) qT[t % DD][t / DD] = q[b * KK * DD + t];
    __syncthreads();

    // phase 1: lane owns n; preload all 64 k values (64 outstanding loads)
    const int n = n0 + wave * 64 + lane;
    const float* kp = kT + (size_t)b * DD * NN + n;
    float kv[DD];
#pragma unroll
    for (int d = 0; d < DD; d++) kv[d] = kp[(size_t)d * NN];

    float dots[KK];
#pragma unroll
    for (int i = 0; i < KK; i++) dots[i] = 0.f;
#pragma unroll
    for (int d = 0; d < DD; d++) {
        const float k_ = kv[d];
        const float4 q0 = *(const float4*)&qT[d][0];
        const float4 q1 = *(const float4*)&qT[d][4];
        dots[0] += k_ * q0.x; dots[1] += k_ * q0.y;
        dots[2] += k_ * q0.z; dots[3] += k_ * q0.w;
        dots[4] += k_ * q1.x; dots[5] += k_ * q1.y;
        dots[6] += k_ * q1.z; dots[7] += k_ * q1.w;
    }
    float m = -1e30f;
#pragma unroll
    for (int i = 0; i < KK; i++) { dots[i] *= SCALE; m = fmaxf(m, dots[i]); }
    float s = 0.f, e[KK];
#pragma unroll
    for (int i = 0; i < KK; i++) { e[i] = __expf(dots[i] - m); s += e[i]; }
    const float inv = 1.f / s;
    float a[KK], sv[KK];
#pragma unroll
    for (int i = 0; i < KK; i++) { a[i] = e[i] * inv + EPS_A; sv[i] = a[i]; }

    const int nl = wave * 64 + lane;
    *(float4*)&al[nl][0] = make_float4(a[0], a[1], a[2], a[3]);
    *(float4*)&al[nl][4] = make_float4(a[4], a[5], a[6], a[7]);
    if (attn_out) {
#pragma unroll
        for (int i = 0; i < KK; i++)
            attn_out[((size_t)b * KK + i) * NN + n] = a[i];
    }
#pragma unroll
    for (int off = 32; off > 0; off >>= 1) {
#pragma unroll
        for (int i = 0; i < KK; i++) sv[i] += __shfl_xor(sv[i], off, 64);
    }
    if (lane == 0) {
#pragma unroll
        for (int i = 0; i < KK; i++) Sr[wave][i] = sv[i];
    }
    __syncthreads();

    // phase 2: lane owns d; wave iterates its 64 n; preload all 64 v values
    const float* vp = v + ((size_t)b * NN + n0 + wave * 64) * DD + lane;
    float vv[64];
#pragma unroll
    for (int t = 0; t < 64; t++) vv[t] = vp[t * DD];

    float U[KK];
#pragma unroll
    for (int i = 0; i < KK; i++) U[i] = 0.f;
#pragma unroll
    for (int t = 0; t < 64; t++) {
        const float vx = vv[t];
        const float4 a0 = *(const float4*)&al[wave * 64 + t][0];
        const float4 a1 = *(const float4*)&al[wave * 64 + t][4];
        U[0] += a0.x * vx; U[1] += a0.y * vx; U[2] += a0.z * vx; U[3] += a0.w * vx;
        U[4] += a1.x * vx; U[5] += a1.y * vx; U[6] += a1.z * vx; U[7] += a1.w * vx;
    }
#pragma unroll
    for (int i = 0; i < KK; i++) Ur[wave][i * DD + lane] = U[i];
    __syncthreads();

    for (int t = tid; t < KK * DD; t += 256) {
        Upart[(size_t)blockIdx.x * KK * DD + t] =
            Ur[0][t] + Ur[1][t] + Ur[2][t] + Ur[3][t];
    }
    if (tid < KK)
        Spart[blockIdx.x * KK + tid] =
            Sr[0][tid] + Sr[1][tid] + Sr[2][tid] + Sr[3][tid];
}

// ---------------------------------------------------------------------------
// K3: one WAVE per (b, slot). Reduce partials -> upd = U/S; GRU + residual
// MLP; next q = LN(slots) @ Wq.  Grid = B*K blocks x 64 threads. Lane owns d.
// ---------------------------------------------------------------------------
__global__ __launch_bounds__(64) void k3_update(
    const float* __restrict__ Upart, const float* __restrict__ Spart,
    const float* __restrict__ h_in, float* __restrict__ slots_cur,
    float* __restrict__ qout,
    const float* __restrict__ gru_wih, const float* __restrict__ gru_whh,
    const float* __restrict__ gru_bih, const float* __restrict__ gru_bhh,
    const float* __restrict__ gbg_wih, const float* __restrict__ gbg_whh,
    const float* __restrict__ gbg_bih, const float* __restrict__ gbg_bhh,
    const float* __restrict__ res_g, const float* __restrict__ res_b,
    const float* __restrict__ res_w1, const float* __restrict__ res_b1,
    const float* __restrict__ res_w2, const float* __restrict__ res_b2,
    const float* __restrict__ rbg_g, const float* __restrict__ rbg_b,
    const float* __restrict__ rbg_w1, const float* __restrict__ rbg_b1,
    const float* __restrict__ rbg_w2, const float* __restrict__ rbg_b2,
    const float* __restrict__ qln_g, const float* __restrict__ qln_b,
    const float* __restrict__ Wq, const float* __restrict__ qbg_g,
    const float* __restrict__ qbg_b, const float* __restrict__ Wqbg,
    float* __restrict__ out_slots, int do_update)
{
    const int blk = blockIdx.x;
    const int b = blk >> 3, i = blk & 7, lane = threadIdx.x;
    __shared__ float upd_s[DD], h_s[DD], lnx_s[DD], h1_s[HH];

    const float h = h_in[(size_t)blk * DD + lane];
    h_s[lane] = h;

    if (do_update) {
        float ssum = (lane < NT) ? Spart[(size_t)(b * NT + lane) * KK + i] : 0.f;
        ssum = wave_sum(ssum);
        float us = 0.f;
#pragma unroll
        for (int p = 0; p < NT; p++)
            us += Upart[((size_t)(b * NT + p) * KK + i) * DD + lane];
        upd_s[lane] = us / ssum;
    }
    __syncthreads();

    float newh = h;
    if (do_update) {
        const float* wih = i ? gru_wih : gbg_wih;
        const float* whh = i ? gru_whh : gbg_whh;
        const float* bih = i ? gru_bih : gbg_bih;
        const float* bhh = i ? gru_bhh : gbg_bhh;
        float gi3[3], gh3[3];
#pragma unroll
        for (int gg = 0; gg < 3; gg++) {
            const int j = gg * DD + lane;
            float si = bih[j], sh = bhh[j];
#pragma unroll
            for (int d4 = 0; d4 < 16; d4++) {
                const float4 wi = *(const float4*)&wih[j * DD + d4 * 4];
                const float4 wh = *(const float4*)&whh[j * DD + d4 * 4];
                const float4 ud = *(const float4*)&upd_s[d4 * 4];
                const float4 hd = *(const float4*)&h_s[d4 * 4];
                si += wi.x * ud.x + wi.y * ud.y + wi.z * ud.z + wi.w * ud.w;
                sh += wh.x * hd.x + wh.y * hd.y + wh.z * hd.z + wh.w * hd.w;
            }
            gi3[gg] = si; gh3[gg] = sh;
        }
        const float r = sigmoidf_(gi3[0] + gh3[0]);
        const float z = sigmoidf_(gi3[1] + gh3[1]);
        const float ng = tanhf(gi3[2] + r * gh3[2]);
        const float tmp = (1.f - z) * ng + z * h;

        // residual MLP
        const float m = wave_sum(tmp) * (1.f / DD);
        const float dv = tmp - m;
        const float var = wave_sum(dv * dv) * (1.f / DD);
        const float lnx = dv * rsqrtf(var + LN_EPS) * (i ? res_g : rbg_g)[lane] +
                          (i ? res_b : rbg_b)[lane];
        lnx_s[lane] = lnx;
        __syncthreads();
        const float* w1 = i ? res_w1 : rbg_w1;
        const float* b1 = i ? res_b1 : rbg_b1;
#pragma unroll
        for (int t = 0; t < 2; t++) {
            const int j = t * DD + lane;
            float sacc = b1[j];
#pragma unroll 16
            for (int d = 0; d < DD; d++) sacc += lnx_s[d] * w1[d * HH + j];
            h1_s[j] = fmaxf(sacc, 0.f);
        }
        __syncthreads();
        const float* w2 = i ? res_w2 : rbg_w2;
        float o = (i ? res_b2 : rbg_b2)[lane];
#pragma unroll 16
        for (int j = 0; j < HH; j++) o += h1_s[j] * w2[j * DD + lane];
        newh = tmp + o;
    }

    slots_cur[(size_t)blk * DD + lane] = newh;
    if (out_slots) out_slots[(size_t)blk * DD + lane] = newh;

    // next q: LN(slots) with q/qbg params, then @ Wq / Wq_bg
    const float m2 = wave_sum(newh) * (1.f / DD);
    const float d2 = newh - m2;
    const float v2 = wave_sum(d2 * d2) * (1.f / DD);
    const float lq = d2 * rsqrtf(v2 + LN_EPS) * (i ? qln_g : qbg_g)[lane] +
                     (i ? qln_b : qbg_b)[lane];
    __syncthreads();
    lnx_s[lane] = lq;
    __syncthreads();
    const float* W = i ? Wq : Wqbg;
    float qv = 0.f;
#pragma unroll 16
    for (int e = 0; e < DD; e++) qv += lnx_s[e] * W[e * DD + lane];
    qout[(size_t)blk * DD + lane] = qv;
}

// ---------------------------------------------------------------------------
extern "C" void kernel_launch(void* const* d_in, const int* in_sizes, int n_in,
                              void* d_out, int out_size, void* d_ws, size_t ws_size,
                              hipStream_t stream)
{
    const float* feat    = (const float*)d_in[0];
    const float* slot_in = (const float*)d_in[1];
    const float* nf_g    = (const float*)d_in[2];
    const float* nf_b    = (const float*)d_in[3];
    const float* Wk      = (const float*)d_in[4];
    const float* Wv      = (const float*)d_in[5];
    const float* qln_g   = (const float*)d_in[6];
    const float* qln_b   = (const float*)d_in[7];
    const float* Wq      = (const float*)d_in[8];
    const float* qbg_g   = (const float*)d_in[9];
    const float* qbg_b   = (const float*)d_in[10];
    const float* Wqbg    = (const float*)d_in[11];
    const float* gru_wih = (const float*)d_in[12];
    const float* gru_whh = (const float*)d_in[13];
    const float* gru_bih = (const float*)d_in[14];
    const float* gru_bhh = (const float*)d_in[15];
    const float* gbg_wih = (const float*)d_in[16];
    const float* gbg_whh = (const float*)d_in[17];
    const float* gbg_bih = (const float*)d_in[18];
    const float* gbg_bhh = (const float*)d_in[19];
    const float* res_g   = (const float*)d_in[20];
    const float* res_b   = (const float*)d_in[21];
    const float* res_w1  = (const float*)d_in[22];
    const float* res_b1  = (const float*)d_in[23];
    const float* res_w2  = (const float*)d_in[24];
    const float* res_b2  = (const float*)d_in[25];
    const float* rbg_g   = (const float*)d_in[26];
    const float* rbg_b   = (const float*)d_in[27];
    const float* rbg_w1  = (const float*)d_in[28];
    const float* rbg_b1  = (const float*)d_in[29];
    const float* rbg_w2  = (const float*)d_in[30];
    const float* rbg_b2  = (const float*)d_in[31];

    float* out = (float*)d_out;
    char* ws = (char*)d_ws;
    size_t off = 0;
    unsigned short* fragW = (unsigned short*)(ws + off); off += 16384 * 2;
    off = (off + 255) & ~(size_t)255;
    float* kT    = (float*)(ws + off); off += (size_t)BB * DD * NN * 4;
    float* v     = (float*)(ws + off); off += (size_t)BB * NN * DD * 4;
    float* q     = (float*)(ws + off); off += (size_t)BB * KK * DD * 4;
    float* slots = (float*)(ws + off); off += (size_t)BB * KK * DD * 4;
    float* Upart = (float*)(ws + off); off += (size_t)BB * NT * KK * DD * 4;
    float* Spart = (float*)(ws + off); off += (size_t)BB * NT * KK * 4;
    if (off > ws_size) return;  // loud failure rather than corruption

    float* out_slots = out;                 // [B][K][D]
    float* out_attn  = out + BB * KK * DD;  // [B][K][N]

    k0_prepw<<<64, 256, 0, stream>>>(Wk, Wv, fragW);

    // init: slots = slot_in, q from initial slots (independent of k1)
    k3_update<<<BB * KK, 64, 0, stream>>>(
        Upart, Spart, slot_in, slots, q,
        gru_wih, gru_whh, gru_bih, gru_bhh, gbg_wih, gbg_whh, gbg_bih, gbg_bhh,
        res_g, res_b, res_w1, res_b1, res_w2, res_b2,
        rbg_g, rbg_b, rbg_w1, rbg_b1, rbg_w2, rbg_b2,
        qln_g, qln_b, Wq, qbg_g, qbg_b, Wqbg, nullptr, 0);

    k1_mfma<<<BB * NN / 64, 256, 0, stream>>>(feat, nf_g, nf_b, fragW, kT, v);

    for (int it = 0; it < 3; it++) {
        k2_attn<<<BB * NT, 256, 0, stream>>>(
            kT, v, q, Upart, Spart, it == 2 ? out_attn : nullptr);
        k3_update<<<BB * KK, 64, 0, stream>>>(
            Upart, Spart, slots, slots, q,
            gru_wih, gru_whh, gru_bih, gru_bhh, gbg_wih, gbg_whh, gbg_bih, gbg_bhh,
            res_g, res_b, res_w1, res_b1, res_w2, res_b2,
            rbg_g, rbg_b, rbg_w1, rbg_b1, rbg_w2, rbg_b2,
            qln_g, qln_b, Wq, qbg_g, qbg_b, Wqbg,
            it == 2 ? out_slots : nullptr, 1);
    }
}

// Round 3
// 268.221 us; speedup vs baseline: 1.6929x; 1.0184x over previous
//
#include <hip/hip_runtime.h>
#include <hip/hip_bf16.h>

// Problem constants
constexpr int BB = 32;     // batch
constexpr int NN = 4096;   // tokens
constexpr int CC = 128;    // feat channels
constexpr int DD = 64;     // slot dim
constexpr int KK = 8;      // slots (slot 0 = bg, 1..7 = fg)
constexpr int HH = 128;    // mlp hidden
constexpr float SCALE = 0.125f;   // D^-0.5
constexpr float EPS_A = 1e-8f;
constexpr float LN_EPS = 1e-5f;

constexpr int NTIL = 64;          // n-tiles per batch in K2 (64 n each)

typedef __bf16 bfx8 __attribute__((ext_vector_type(8)));
typedef float f32x4 __attribute__((ext_vector_type(4)));

__device__ inline float wave_sum(float x) {
#pragma unroll
    for (int off = 32; off > 0; off >>= 1) x += __shfl_xor(x, off, 64);
    return x;
}

__device__ inline float lane_bcast(float v, int src) {
    return __uint_as_float(__builtin_amdgcn_readlane(__float_as_uint(v), src));
}

__device__ inline float sigmoidf_(float x) { return 1.f / (1.f + __expf(-x)); }

// round-to-nearest-even bf16 (bit trick; inputs finite & moderate)
__device__ inline unsigned short bf16rne(float x) {
    unsigned u = __float_as_uint(x);
    unsigned r = u + 0x7fffu + ((u >> 16) & 1u);
    return (unsigned short)(r >> 16);
}
__device__ inline float bf16tof(unsigned short h) {
    return __uint_as_float(((unsigned)h) << 16);
}

// ---------------------------------------------------------------------------
// K0a: build fragment-linear bf16 W = [Wk | Wv]  (shape [C=128][N=128]).
// fragW layout: [ks(4)][nf(8)][lane(64)][j(8)] bf16, element =
// W[ks*32 + (lane>>4)*8 + j][nf*16 + (lane&15)].  16384 elems = 32 KB.
// ---------------------------------------------------------------------------
__global__ __launch_bounds__(256) void k0_prepw(
    const float* __restrict__ Wk, const float* __restrict__ Wv,
    unsigned short* __restrict__ fragW)
{
    const int o = blockIdx.x * 256 + threadIdx.x;   // < 16384
    const int j = o & 7, l = (o >> 3) & 63, nf = (o >> 9) & 7, ks = o >> 12;
    const int c = ks * 32 + ((l >> 4) << 3) + j;
    const int n = nf * 16 + (l & 15);
    const float w = (n < DD) ? Wk[c * DD + n] : Wv[c * DD + (n - DD)];
    fragW[o] = bf16rne(w);
}

// ---------------------------------------------------------------------------
// K0b: transpose the 4 GRU weight matrices [192][64] -> wT[m][64][192] so K3's
// matvec loads are lane-coalesced.  m: 0=fg_ih 1=fg_hh 2=bg_ih 3=bg_hh.
// ---------------------------------------------------------------------------
__global__ __launch_bounds__(256) void k0_prepg(
    const float* __restrict__ fg_ih, const float* __restrict__ fg_hh,
    const float* __restrict__ bg_ih, const float* __restrict__ bg_hh,
    float* __restrict__ wT)
{
    const int o = blockIdx.x * 256 + threadIdx.x;   // < 4*64*192 = 49152
    const int m = o / (DD * 3 * DD);
    const int rem = o % (DD * 3 * DD);
    const int d = rem / (3 * DD), j = rem % (3 * DD);
    const float* W = (m == 0) ? fg_ih : (m == 1) ? fg_hh : (m == 2) ? bg_ih : bg_hh;
    wT[o] = W[j * DD + d];
}

// ---------------------------------------------------------------------------
// K1: x = LN(feat); [k|v] = x @ W via bf16 MFMA with 2-term split (x_hi+x_lo).
// Block 256 thr (4 waves), tile M=64 rows, N=128 (k cols 0-63, v cols 64-127).
// LDS 32KB: xh_hi|xh_lo bf16 (packed b32 writes, XOR-16B swizzle), reused as
// ks[64][65] fp32 transpose buffer.  B-frags read straight from global (L2).
// ---------------------------------------------------------------------------
__global__ __launch_bounds__(256, 4) void k1_mfma(
    const float* __restrict__ feat, const float* __restrict__ nf_g,
    const float* __restrict__ nf_b, const unsigned short* __restrict__ fragW,
    float* __restrict__ kT, float* __restrict__ vout)
{
    __shared__ char ubuf[32768];   // xh_hi[16K] | xh_lo[16K]  /  ks[64][65] f32

    const int tid = threadIdx.x, w = tid >> 6, lane = tid & 63;
    const size_t row0 = (size_t)blockIdx.x * 64;

    const float2 g2 = *(const float2*)&nf_g[2 * lane];
    const float2 b2 = *(const float2*)&nf_b[2 * lane];

    // LN: wave w handles rows w*16..+15; lane owns 2 ADJACENT cols -> packed
    // b32 bf16 writes (conflict-free: bank = lane ^ swz-bits, all distinct).
#pragma unroll 4
    for (int r0 = 0; r0 < 16; r0++) {
        const int r = w * 16 + r0;
        const float2 x2 = *(const float2*)&feat[(row0 + r) * CC + 2 * lane];
        const float m = wave_sum(x2.x + x2.y) * (1.f / 128.f);
        const float d0 = x2.x - m, d1 = x2.y - m;
        const float var = wave_sum(d0 * d0 + d1 * d1) * (1.f / 128.f);
        const float rs = rsqrtf(var + LN_EPS);
        const float y0 = d0 * rs * g2.x + b2.x;
        const float y1 = d1 * rs * g2.y + b2.y;
        const unsigned short h0 = bf16rne(y0), h1 = bf16rne(y1);
        const unsigned short l0 = bf16rne(y0 - bf16tof(h0));
        const unsigned short l1 = bf16rne(y1 - bf16tof(h1));
        const int off = r * 256 + ((4 * lane) ^ ((r & 7) << 4));
        *(unsigned*)(ubuf + off) = (unsigned)h0 | ((unsigned)h1 << 16);
        *(unsigned*)(ubuf + 16384 + off) = (unsigned)l0 | ((unsigned)l1 << 16);
    }
    __syncthreads();

    // MFMA: wave w owns rows w*16..+15; 8 N-frags; 4 K-steps; 2 terms
    f32x4 acc[8];
#pragma unroll
    for (int nf = 0; nf < 8; nf++) acc[nf] = (f32x4){0.f, 0.f, 0.f, 0.f};

    const int arow = w * 16 + (lane & 15);
    const int hi16 = lane >> 4;
    const int asw = (arow & 7) << 4;
#pragma unroll
    for (int ks = 0; ks < 4; ks++) {
        const int abyte = arow * 256 + ((ks * 64 + hi16 * 16) ^ asw);
        const bfx8 ah = __builtin_bit_cast(bfx8, *(const uint4*)(ubuf + abyte));
        const bfx8 al = __builtin_bit_cast(bfx8, *(const uint4*)(ubuf + 16384 + abyte));
#pragma unroll
        for (int nf = 0; nf < 8; nf++) {
            const bfx8 bw = __builtin_bit_cast(
                bfx8, *(const uint4*)(fragW + ((ks * 8 + nf) * 64 + lane) * 8));
            acc[nf] = __builtin_amdgcn_mfma_f32_16x16x32_bf16(ah, bw, acc[nf], 0, 0, 0);
            acc[nf] = __builtin_amdgcn_mfma_f32_16x16x32_bf16(al, bw, acc[nf], 0, 0, 0);
        }
    }
    __syncthreads();   // xh dead; reuse ubuf as ks[64][65]

    float* kslds = (float*)ubuf;
    const int trow = w * 16 + (lane >> 4) * 4;   // C-frag: row=(lane>>4)*4+reg
    // k-part (nf 0..3) -> LDS transpose; v-part (nf 4..7) -> direct store
#pragma unroll
    for (int nf = 0; nf < 4; nf++) {
        const int d = nf * 16 + (lane & 15);
#pragma unroll
        for (int reg = 0; reg < 4; reg++)
            kslds[d * 65 + trow + reg] = acc[nf][reg];
    }
    {
        const size_t vbase = (row0 + trow) * DD + (lane & 15);
#pragma unroll
        for (int nf = 4; nf < 8; nf++) {
#pragma unroll
            for (int reg = 0; reg < 4; reg++)
                vout[vbase + (size_t)reg * DD + (nf - 4) * 16] = acc[nf][reg];
        }
    }
    __syncthreads();

    const int b = (int)(row0 >> 12);          // NN = 4096
    const int n0 = (int)(row0 & 4095);
#pragma unroll
    for (int t = 0; t < 16; t++) {
        const int idx = t * 256 + tid;
        const int d = idx >> 6, nn = idx & 63;
        kT[((size_t)b * DD + d) * NN + n0 + nn] = kslds[d * 65 + nn];
    }
}

// ---------------------------------------------------------------------------
// K2: one WAVE per (b, 64-n tile).  Zero LDS: q and attn values move via
// v_readlane (SALU pipe).  dots = q.kT*SCALE -> lane-local softmax over 8
// slots (+eps) -> per-wave partials S[i], U[i][d].
// ---------------------------------------------------------------------------
__global__ __launch_bounds__(64) void k2_attn(
    const float* __restrict__ kT, const float* __restrict__ v,
    const float* __restrict__ q, float* __restrict__ Upart,
    float* __restrict__ Spart, float* __restrict__ attn_out)
{
    const int blk = blockIdx.x;            // b*64 + tile
    const int b = blk >> 6, tile = blk & 63;
    const int lane = threadIdx.x;
    const int n = (tile << 6) + lane;

    // q fragment: lane holds q[i][lane] for all 8 slots (coalesced loads)
    float qreg[KK];
#pragma unroll
    for (int i = 0; i < KK; i++) qreg[i] = q[((size_t)b * KK + i) * DD + lane];

    // phase 1: lane owns n; preload the 64-deep k column
    const float* kp = kT + (size_t)b * DD * NN + n;
    float kv[DD];
#pragma unroll
    for (int d = 0; d < DD; d++) kv[d] = kp[(size_t)d * NN];

    float dots[KK];
#pragma unroll
    for (int i = 0; i < KK; i++) dots[i] = 0.f;
#pragma unroll
    for (int d = 0; d < DD; d++) {
        const float k_ = kv[d];
#pragma unroll
        for (int i = 0; i < KK; i++)
            dots[i] += k_ * lane_bcast(qreg[i], d);   // v_readlane: SALU
    }
    float m = -1e30f;
#pragma unroll
    for (int i = 0; i < KK; i++) { dots[i] *= SCALE; m = fmaxf(m, dots[i]); }
    float s = 0.f, e[KK];
#pragma unroll
    for (int i = 0; i < KK; i++) { e[i] = __expf(dots[i] - m); s += e[i]; }
    const float inv = 1.f / s;
    float a[KK], sv[KK];
#pragma unroll
    for (int i = 0; i < KK; i++) { a[i] = e[i] * inv + EPS_A; sv[i] = a[i]; }

    if (attn_out) {
#pragma unroll
        for (int i = 0; i < KK; i++)
            attn_out[((size_t)b * KK + i) * NN + n] = a[i];
    }
#pragma unroll
    for (int off = 32; off > 0; off >>= 1) {
#pragma unroll
        for (int i = 0; i < KK; i++) sv[i] += __shfl_xor(sv[i], off, 64);
    }
    if (lane < KK) Spart[(size_t)blk * KK + lane] = sv[lane];  // hmm: lane i stores sv[i]? No.

    // phase 2: lane owns d; iterate the wave's own 64 n via readlane
    const float* vp = v + ((size_t)b * NN + (tile << 6)) * DD + lane;
    float vv[64];
#pragma unroll
    for (int t = 0; t < 64; t++) vv[t] = vp[t * DD];

    float U[KK];
#pragma unroll
    for (int i = 0; i < KK; i++) U[i] = 0.f;
#pragma unroll
    for (int t = 0; t < 64; t++) {
        const float vx = vv[t];
#pragma unroll
        for (int i = 0; i < KK; i++)
            U[i] += lane_bcast(a[i], t) * vx;
    }
#pragma unroll
    for (int i = 0; i < KK; i++)
        Upart[((size_t)blk * KK + i) * DD + lane] = U[i];
}

// ---------------------------------------------------------------------------
// K3: one block of 384 thr per (b, slot).  upd = SUM(Upart)/SUM(Spart); GRU
// (transposed weights, coalesced) + residual MLP; next q = LN(slots) @ Wq.
// ---------------------------------------------------------------------------
__global__ __launch_bounds__(384) void k3_update(
    const float* __restrict__ Upart, const float* __restrict__ Spart,
    const float* __restrict__ h_in, float* __restrict__ slots_cur,
    float* __restrict__ qout, const float* __restrict__ wT,
    const float* __restrict__ gru_bih, const float* __restrict__ gru_bhh,
    const float* __restrict__ gbg_bih, const float* __restrict__ gbg_bhh,
    const float* __restrict__ res_g, const float* __restrict__ res_b,
    const float* __restrict__ res_w1, const float* __restrict__ res_b1,
    const float* __restrict__ res_w2, const float* __restrict__ res_b2,
    const float* __restrict__ rbg_g, const float* __restrict__ rbg_b,
    const float* __restrict__ rbg_w1, const float* __restrict__ rbg_b1,
    const float* __restrict__ rbg_w2, const float* __restrict__ rbg_b2,
    const float* __restrict__ qln_g, const float* __restrict__ qln_b,
    const float* __restrict__ Wq, const float* __restrict__ qbg_g,
    const float* __restrict__ qbg_b, const float* __restrict__ Wqbg,
    float* __restrict__ out_slots, int do_update)
{
    const int blk = blockIdx.x;          // b*8 + i
    const int b = blk >> 3, i = blk & 7;
    const int t = threadIdx.x;
    const int fg = (i != 0);

    __shared__ float h_s[DD], upd_s[DD], red[4][DD],
        gih_s[3 * DD], ghh_s[3 * DD], lnx_s[DD], h1_s[HH];

    if (t < DD) h_s[t] = h_in[(size_t)blk * DD + t];

    float sp = 0.f;
    if (do_update) {
        if (t < 256) {
            const int d = t & 63, g = t >> 6;
            float sacc = 0.f;
#pragma unroll
            for (int p = 0; p < 16; p++)
                sacc += Upart[((size_t)(b * NTIL + g * 16 + p) * KK + i) * DD + d];
            red[g][d] = sacc;
        }
        if (t < 64) {
            sp = Spart[(size_t)(b * NTIL + t) * KK + i];
            sp = wave_sum(sp);
        }
        __syncthreads();
        if (t < 64)
            upd_s[t] = (red[0][t] + red[1][t] + red[2][t] + red[3][t]) / sp;
        __syncthreads();

        // dual GRU matvec: waves 0-2 -> gi (192 j), waves 3-5 -> gh (192 j)
        {
            const int isIH = (t < 3 * DD);
            const int j = isIH ? t : t - 3 * DD;
            const float* w = wT + (size_t)((fg ? 0 : 2) + (isIH ? 0 : 1)) * (DD * 3 * DD);
            const float* xs = isIH ? upd_s : h_s;
            const float* bias = isIH ? (fg ? gru_bih : gbg_bih)
                                     : (fg ? gru_bhh : gbg_bhh);
            float acc = bias[j];
#pragma unroll
            for (int d4 = 0; d4 < 16; d4++) {
                const float4 xv = *(const float4*)&xs[d4 * 4];
                acc += xv.x * w[(d4 * 4 + 0) * 192 + j];
                acc += xv.y * w[(d4 * 4 + 1) * 192 + j];
                acc += xv.z * w[(d4 * 4 + 2) * 192 + j];
                acc += xv.w * w[(d4 * 4 + 3) * 192 + j];
            }
            if (isIH) gih_s[j] = acc; else ghh_s[j] = acc;
        }
        __syncthreads();
    }

    float tmpv = 0.f, newh = 0.f;
    if (do_update) {
        if (t < 64) {
            const float r = sigmoidf_(gih_s[t] + ghh_s[t]);
            const float z = sigmoidf_(gih_s[DD + t] + ghh_s[DD + t]);
            const float ng = tanhf(gih_s[2 * DD + t] + r * ghh_s[2 * DD + t]);
            tmpv = (1.f - z) * ng + z * h_s[t];
            const float m = wave_sum(tmpv) * (1.f / DD);
            const float dv = tmpv - m;
            const float var = wave_sum(dv * dv) * (1.f / DD);
            lnx_s[t] = dv * rsqrtf(var + LN_EPS) * (fg ? res_g : rbg_g)[t] +
                       (fg ? res_b : rbg_b)[t];
        }
        __syncthreads();
        if (t < HH) {
            const float* w1 = fg ? res_w1 : rbg_w1;
            float acc = (fg ? res_b1 : rbg_b1)[t];
#pragma unroll
            for (int d4 = 0; d4 < 16; d4++) {
                const float4 xv = *(const float4*)&lnx_s[d4 * 4];
                acc += xv.x * w1[(d4 * 4 + 0) * HH + t];
                acc += xv.y * w1[(d4 * 4 + 1) * HH + t];
                acc += xv.z * w1[(d4 * 4 + 2) * HH + t];
                acc += xv.w * w1[(d4 * 4 + 3) * HH + t];
            }
            h1_s[t] = fmaxf(acc, 0.f);
        }
        __syncthreads();
        if (t < 64) {
            const float* w2 = fg ? res_w2 : rbg_w2;
            float o = (fg ? res_b2 : rbg_b2)[t];
#pragma unroll
            for (int j4 = 0; j4 < 32; j4++) {
                const float4 hv = *(const float4*)&h1_s[j4 * 4];
                o += hv.x * w2[(j4 * 4 + 0) * DD + t];
                o += hv.y * w2[(j4 * 4 + 1) * DD + t];
                o += hv.z * w2[(j4 * 4 + 2) * DD + t];
                o += hv.w * w2[(j4 * 4 + 3) * DD + t];
            }
            newh = tmpv + o;
        }
    } else {
        if (t < 64) newh = h_s[t];
    }

    if (t < 64) {
        slots_cur[(size_t)blk * DD + t] = newh;
        if (out_slots) out_slots[(size_t)blk * DD + t] = newh;

        const float m2 = wave_sum(newh) * (1.f / DD);
        const float d2 = newh - m2;
        const float v2 = wave_sum(d2 * d2) * (1.f / DD);
        lnx_s[t] = d2 * rsqrtf(v2 + LN_EPS) * (fg ? qln_g : qbg_g)[t] +
                   (fg ? qln_b : qbg_b)[t];
        __builtin_amdgcn_s_waitcnt(0);   // same-wave LDS write->read ordering
        const float* W = fg ? Wq : Wqbg;
        float qv = 0.f;
#pragma unroll
        for (int e4 = 0; e4 < 16; e4++) {
            const float4 xv = *(const float4*)&lnx_s[e4 * 4];
            qv += xv.x * W[(e4 * 4 + 0) * DD + t];
            qv += xv.y * W[(e4 * 4 + 1) * DD + t];
            qv += xv.z * W[(e4 * 4 + 2) * DD + t];
            qv += xv.w * W[(e4 * 4 + 3) * DD + t];
        }
        qout[(size_t)blk * DD + t] = qv;
    }
}

// ---------------------------------------------------------------------------
extern "C" void kernel_launch(void* const* d_in, const int* in_sizes, int n_in,
                              void* d_out, int out_size, void* d_ws, size_t ws_size,
                              hipStream_t stream)
{
    const float* feat    = (const float*)d_in[0];
    const float* slot_in = (const float*)d_in[1];
    const float* nf_g    = (const float*)d_in[2];
    const float* nf_b    = (const float*)d_in[3];
    const float* Wk      = (const float*)d_in[4];
    const float* Wv      = (const float*)d_in[5];
    const float* qln_g   = (const float*)d_in[6];
    const float* qln_b   = (const float*)d_in[7];
    const float* Wq      = (const float*)d_in[8];
    const float* qbg_g   = (const float*)d_in[9];
    const float* qbg_b   = (const float*)d_in[10];
    const float* Wqbg    = (const float*)d_in[11];
    const float* gru_wih = (const float*)d_in[12];
    const float* gru_whh = (const float*)d_in[13];
    const float* gru_bih = (const float*)d_in[14];
    const float* gru_bhh = (const float*)d_in[15];
    const float* gbg_wih = (const float*)d_in[16];
    const float* gbg_whh = (const float*)d_in[17];
    const float* gbg_bih = (const float*)d_in[18];
    const float* gbg_bhh = (const float*)d_in[19];
    const float* res_g   = (const float*)d_in[20];
    const float* res_b   = (const float*)d_in[21];
    const float* res_w1  = (const float*)d_in[22];
    const float* res_b1  = (const float*)d_in[23];
    const float* res_w2  = (const float*)d_in[24];
    const float* res_b2  = (const float*)d_in[25];
    const float* rbg_g   = (const float*)d_in[26];
    const float* rbg_b   = (const float*)d_in[27];
    const float* rbg_w1  = (const float*)d_in[28];
    const float* rbg_b1  = (const float*)d_in[29];
    const float* rbg_w2  = (const float*)d_in[30];
    const float* rbg_b2  = (const float*)d_in[31];

    float* out = (float*)d_out;
    char* ws = (char*)d_ws;
    size_t off = 0;
    unsigned short* fragW = (unsigned short*)(ws + off); off += 16384 * 2;
    off = (off + 255) & ~(size_t)255;
    float* wT    = (float*)(ws + off); off += 4 * DD * 3 * DD * 4;
    float* kT    = (float*)(ws + off); off += (size_t)BB * DD * NN * 4;
    float* v     = (float*)(ws + off); off += (size_t)BB * NN * DD * 4;
    float* q     = (float*)(ws + off); off += (size_t)BB * KK * DD * 4;
    float* slots = (float*)(ws + off); off += (size_t)BB * KK * DD * 4;
    float* Upart = (float*)(ws + off); off += (size_t)BB * NTIL * KK * DD * 4;
    float* Spart = (float*)(ws + off); off += (size_t)BB * NTIL * KK * 4;
    if (off > ws_size) return;  // loud failure rather than corruption

    float* out_slots = out;                 // [B][K][D]
    float* out_attn  = out + BB * KK * DD;  // [B][K][N]

    k0_prepw<<<64, 256, 0, stream>>>(Wk, Wv, fragW);
    k0_prepg<<<192, 256, 0, stream>>>(gru_wih, gru_whh, gbg_wih, gbg_whh, wT);

    // init: slots = slot_in, q from initial slots
    k3_update<<<BB * KK, 384, 0, stream>>>(
        Upart, Spart, slot_in, slots, q, wT,
        gru_bih, gru_bhh, gbg_bih, gbg_bhh,
        res_g, res_b, res_w1, res_b1, res_w2, res_b2,
        rbg_g, rbg_b, rbg_w1, rbg_b1, rbg_w2, rbg_b2,
        qln_g, qln_b, Wq, qbg_g, qbg_b, Wqbg, nullptr, 0);

    k1_mfma<<<BB * NN / 64, 256, 0, stream>>>(feat, nf_g, nf_b, fragW, kT, v);

    for (int it = 0; it < 3; it++) {
        k2_attn<<<BB * NTIL, 64, 0, stream>>>(
            kT, v, q, Upart, Spart, it == 2 ? out_attn : nullptr);
        k3_update<<<BB * KK, 384, 0, stream>>>(
            Upart, Spart, slots, slots, q, wT,
            gru_bih, gru_bhh, gbg_bih, gbg_bhh,
            res_g, res_b, res_w1, res_b1, res_w2, res_b2,
            rbg_g, rbg_b, rbg_w1, rbg_b1, rbg_w2, rbg_b2,
            qln_g, qln_b, Wq, qbg_g, qbg_b, Wqbg,
            it == 2 ? out_slots : nullptr, 1);
    }
}